// Round 1
// baseline (1128.819 us; speedup 1.0000x reference)
//
#include <hip/hip_runtime.h>
#include <math.h>

#define N_NODES 50000
#define E1N 400000
#define E2N 100000
#define E_TOT 500000
#define ALPHAC 0.2f
#define DAMP 0.85f
#define EPSC 1e-12f

typedef __bf16 bf16_t;
typedef __bf16 bf16x4 __attribute__((ext_vector_type(4)));
typedef __bf16 bf16x8 __attribute__((ext_vector_type(8)));
typedef float f32x4 __attribute__((ext_vector_type(4)));

__device__ __forceinline__ float lrelu(float x) { return x > 0.f ? x : ALPHAC * x; }

// K0: pack B operand (a[128][384]) into MFMA fragment order, bf16.
// bpack[((ks*8+nt)*64+lane)*8+j] = a[nt*16+(lane&15)][ks*32+(lane>>4)*8+j]
__global__ __launch_bounds__(256) void k_pack(const float* __restrict__ a,
                                              bf16_t* __restrict__ bpack) {
  int i = blockIdx.x * 256 + threadIdx.x;
  if (i >= 12 * 8 * 64 * 8) return;
  int j = i & 7;
  int l = (i >> 3) & 63;
  int nt = (i >> 9) & 7;
  int ks = i >> 12;
  int k = ks * 32 + (l >> 4) * 8 + j;
  int o = nt * 16 + (l & 15);
  bpack[i] = (bf16_t)a[o * 384 + k];
}

// K0b: unified src/dst index arrays (stride handles int32 vs int64 input)
__global__ __launch_bounds__(256) void k_edges(const int* __restrict__ edge,
                                               const int* __restrict__ nhop,
                                               int* __restrict__ sidx,
                                               int* __restrict__ didx, int stride) {
  int e = blockIdx.x * 256 + threadIdx.x;
  if (e >= E_TOT) return;
  if (e < E1N) {
    sidx[e] = edge[(size_t)e * stride];
    didx[e] = edge[(size_t)(E1N + e) * stride];
  } else {
    int t = e - E1N;
    sidx[e] = nhop[(size_t)t * stride];
    didx[e] = nhop[(size_t)(E2N + t) * stride];
  }
}

// The edge-MLP GEMM. ACCUM=false: compute edge_e = exp(-lrelu(lrelu(C)@a2)).
// ACCUM=true: recompute C, atomicAdd lrelu(C)*w[e] into hout[dst].
template <bool ACCUM>
__global__ __launch_bounds__(256) void k_gemm(
    const float* __restrict__ input, const float* __restrict__ eemb,
    const float* __restrict__ eembn, const int* __restrict__ sidx,
    const int* __restrict__ didx, const bf16_t* __restrict__ bpack,
    const float* __restrict__ a2, float* __restrict__ edge_e,
    const float* __restrict__ w, float* __restrict__ hout) {
  __shared__ bf16_t h_tile[64][392];  // +8 bf16 pad: conflict-free ds_read_b128
  __shared__ int s_src[64];
  __shared__ int s_dst[64];
  const int tid = threadIdx.x;
  const long long e0 = (long long)blockIdx.x * 64;

  if (tid < 64) {
    long long e = e0 + tid;
    int s = 0, d = 0;
    if (e < E_TOT) { s = sidx[e]; d = didx[e]; }
    s_src[tid] = s;
    s_dst[tid] = d;
  }
  __syncthreads();

  // Stage 64 x 384 features (x_src | x_dst | emb) as bf16 into LDS.
#pragma unroll
  for (int it = 0; it < 24; ++it) {
    int idx = it * 256 + tid;   // 0..6143 float4s
    int el = idx / 96;          // edge in tile
    int q = idx - el * 96;      // float4 within 384-row
    int seg = q >> 5, c4 = q & 31;
    long long e = e0 + el;
    float4 v = make_float4(0.f, 0.f, 0.f, 0.f);
    if (e < E_TOT) {
      const float4* p;
      if (seg == 0)
        p = (const float4*)(input + (long long)s_src[el] * 128);
      else if (seg == 1)
        p = (const float4*)(input + (long long)s_dst[el] * 128);
      else
        p = (e < E1N) ? (const float4*)(eemb + e * 128)
                      : (const float4*)(eembn + (e - E1N) * 128);
      v = p[c4];
    }
    bf16x4 hv = {(bf16_t)v.x, (bf16_t)v.y, (bf16_t)v.z, (bf16_t)v.w};
    *(bf16x4*)&h_tile[el][q * 4] = hv;
  }
  __syncthreads();

  const int lane = tid & 63;
  const int wv = tid >> 6;
  const int m0 = wv * 16;            // this wave's 16 edges
  const int l15 = lane & 15, hi = lane >> 4;

  f32x4 acc[8];
  const f32x4 zero4 = {0.f, 0.f, 0.f, 0.f};
#pragma unroll
  for (int i = 0; i < 8; ++i) acc[i] = zero4;

  const bf16_t* arow = &h_tile[m0 + l15][0];
  const bf16x8* bp = (const bf16x8*)bpack;
#pragma unroll
  for (int ks = 0; ks < 12; ++ks) {
    bf16x8 af = *(const bf16x8*)(arow + ks * 32 + hi * 8);
#pragma unroll
    for (int nt = 0; nt < 8; ++nt) {
      bf16x8 bfrag = bp[(ks * 8 + nt) * 64 + lane];
      acc[nt] = __builtin_amdgcn_mfma_f32_16x16x32_bf16(af, bfrag, acc[nt], 0, 0, 0);
    }
  }
  // C layout: row(m) = hi*4 + r, col(o) = nt*16 + l15

  if (!ACCUM) {
    float s[4] = {0.f, 0.f, 0.f, 0.f};
#pragma unroll
    for (int nt = 0; nt < 8; ++nt) {
      float a2v = a2[nt * 16 + l15];
#pragma unroll
      for (int r = 0; r < 4; ++r) s[r] += lrelu(acc[nt][r]) * a2v;
    }
#pragma unroll
    for (int off = 1; off < 16; off <<= 1) {
#pragma unroll
      for (int r = 0; r < 4; ++r) s[r] += __shfl_xor(s[r], off, 64);
    }
    if (l15 == 0) {
      long long eb = e0 + m0 + hi * 4;
#pragma unroll
      for (int r = 0; r < 4; ++r) {
        long long e = eb + r;
        if (e < E_TOT) edge_e[e] = expf(-lrelu(s[r]));
      }
    }
  } else {
    long long eb = e0 + m0 + hi * 4;
    float wgt[4];
    int dn[4];
#pragma unroll
    for (int r = 0; r < 4; ++r) {
      long long e = eb + r;
      bool ok = e < E_TOT;
      wgt[r] = ok ? w[e] : 0.f;
      dn[r] = ok ? s_dst[m0 + hi * 4 + r] : -1;
    }
#pragma unroll
    for (int nt = 0; nt < 8; ++nt) {
      int o = nt * 16 + l15;
#pragma unroll
      for (int r = 0; r < 4; ++r) {
        if (dn[r] >= 0)
          atomicAdd(&hout[(long long)dn[r] * 128 + o], lrelu(acc[nt][r]) * wgt[r]);
      }
    }
  }
}

__global__ __launch_bounds__(256) void k_arowsum(const float* __restrict__ edge_e,
                                                 const int* __restrict__ didx,
                                                 float* __restrict__ a_rowsum) {
  int e = blockIdx.x * 256 + threadIdx.x;
  if (e < E_TOT) atomicAdd(&a_rowsum[didx[e]], edge_e[e]);
}

__global__ __launch_bounds__(256) void k_relatt(const float* __restrict__ edge_e,
                                                const int* __restrict__ didx,
                                                const int* __restrict__ sidx,
                                                const float* __restrict__ a_rowsum,
                                                float* __restrict__ rel_att,
                                                float* __restrict__ e_rowsum) {
  int e = blockIdx.x * 256 + threadIdx.x;
  if (e >= E_TOT) return;
  float rs = a_rowsum[didx[e]];
  rs = (rs == 0.f) ? EPSC : rs;
  float r = edge_e[e] / rs;
  rel_att[e] = r;
  atomicAdd(&e_rowsum[sidx[e]], r);
}

__global__ __launch_bounds__(256) void k_val(const float* __restrict__ rel_att,
                                             const int* __restrict__ sidx,
                                             const int* __restrict__ didx,
                                             const float* __restrict__ rank,
                                             const float* __restrict__ e_rowsum,
                                             float* __restrict__ e_colsum) {
  int e = blockIdx.x * 256 + threadIdx.x;
  if (e >= E_TOT) return;
  int s = sidx[e];
  float er = e_rowsum[s];
  er = (er == 0.f) ? EPSC : er;
  float val = rel_att[e] * rank[s] / er;
  atomicAdd(&e_colsum[didx[e]], val);
}

__global__ __launch_bounds__(256) void k_rank(const float* __restrict__ e_colsum,
                                              float* __restrict__ new_rank,
                                              float* __restrict__ out_tail) {
  int n = blockIdx.x * 256 + threadIdx.x;
  if (n >= N_NODES) return;
  float nr = 1.f - DAMP + DAMP * e_colsum[n];
  new_rank[n] = nr;
  out_tail[n] = nr;
}

__global__ __launch_bounds__(256) void k_w(const float* __restrict__ rel_att,
                                           const int* __restrict__ sidx,
                                           const float* __restrict__ new_rank,
                                           float* __restrict__ w) {
  int e = blockIdx.x * 256 + threadIdx.x;
  if (e < E_TOT) w[e] = rel_att[e] * new_rank[sidx[e]];
}

__global__ __launch_bounds__(256) void k_elu(float* __restrict__ h) {
  int i = blockIdx.x * 256 + threadIdx.x;
  if (i < N_NODES * 128) {
    float x = h[i];
    h[i] = x > 0.f ? x : expm1f(x);
  }
}

extern "C" void kernel_launch(void* const* d_in, const int* in_sizes, int n_in,
                              void* d_out, int out_size, void* d_ws, size_t ws_size,
                              hipStream_t stream) {
  const float* input = (const float*)d_in[0];
  const int* edge = (const int*)d_in[1];
  const float* eemb = (const float*)d_in[2];
  const int* enh = (const int*)d_in[3];
  const float* eembn = (const float*)d_in[4];
  const float* rank = (const float*)d_in[5];
  const float* a = (const float*)d_in[6];
  const float* a2 = (const float*)d_in[7];
  float* out = (float*)d_out;

  // int64 edges would arrive as 2x the element count of int32 words
  int estride = (in_sizes[1] == 2 * E1N) ? 1 : 2;

  char* ws = (char*)d_ws;
  bf16_t* bpack = (bf16_t*)(ws);                      // 98304 B
  int* sidx = (int*)(ws + 98304);                     // 2,000,000 B
  int* didx = (int*)(ws + 2098304);                   // 2,000,000 B
  float* edge_e = (float*)(ws + 4098304);             // 2,000,000 B
  float* rel_att = (float*)(ws + 6098304);            // 2,000,000 B
  float* wgt = (float*)(ws + 8098304);                // 2,000,000 B
  float* a_rowsum = (float*)(ws + 10098304);          // 200,000 B
  float* e_rowsum = (float*)(ws + 10298304);          // 200,000 B
  float* e_colsum = (float*)(ws + 10498304);          // 200,000 B
  float* new_rank = (float*)(ws + 10698304);          // 200,000 B

  // zero accumulators (a_rowsum, e_rowsum, e_colsum contiguous) + output acc
  hipMemsetAsync(a_rowsum, 0, 3 * 200000, stream);
  hipMemsetAsync(out, 0, (size_t)N_NODES * 128 * 4, stream);

  k_pack<<<192, 256, 0, stream>>>(a, bpack);
  k_edges<<<(E_TOT + 255) / 256, 256, 0, stream>>>(edge, enh, sidx, didx, estride);

  const int NB = (E_TOT + 63) / 64;
  k_gemm<false><<<NB, 256, 0, stream>>>(input, eemb, eembn, sidx, didx, bpack, a2,
                                        edge_e, nullptr, nullptr);
  const int EB = (E_TOT + 255) / 256;
  k_arowsum<<<EB, 256, 0, stream>>>(edge_e, didx, a_rowsum);
  k_relatt<<<EB, 256, 0, stream>>>(edge_e, didx, sidx, a_rowsum, rel_att, e_rowsum);
  k_val<<<EB, 256, 0, stream>>>(rel_att, sidx, didx, rank, e_rowsum, e_colsum);
  k_rank<<<(N_NODES + 255) / 256, 256, 0, stream>>>(e_colsum, new_rank,
                                                    out + (size_t)N_NODES * 128);
  k_w<<<EB, 256, 0, stream>>>(rel_att, sidx, new_rank, wgt);
  k_gemm<true><<<NB, 256, 0, stream>>>(input, eemb, eembn, sidx, didx, bpack, a2,
                                       nullptr, wgt, out);
  k_elu<<<(N_NODES * 128 + 255) / 256, 256, 0, stream>>>(out);
}

// Round 2
// 845.240 us; speedup vs baseline: 1.3355x; 1.3355x over previous
//
#include <hip/hip_runtime.h>
#include <math.h>

#define N_NODES 50000
#define E1N 400000
#define E2N 100000
#define E_TOT 500000
#define ALPHAC 0.2f
#define DAMP 0.85f
#define EPSC 1e-12f

typedef __bf16 bf16_t;
typedef __bf16 bf16x8 __attribute__((ext_vector_type(8)));
typedef float f32x16 __attribute__((ext_vector_type(16)));

__device__ __forceinline__ float lrelu(float x) { return x > 0.f ? x : ALPHAC * x; }

// Pack a[128][384] into 32x32x16 MFMA B-fragment order (bf16):
// bp[((ks*4+nt)*64+lane)*8+j] = a[nt*32+(lane&31)][ks*16+(lane>>5)*8+j]
__global__ __launch_bounds__(256) void k_pack(const float* __restrict__ a,
                                              bf16_t* __restrict__ bp) {
  int i = blockIdx.x * 256 + threadIdx.x;  // 24*4*64*8 = 49152 exactly
  int j = i & 7;
  int l = (i >> 3) & 63;
  int nt = (i >> 9) & 3;
  int ks = i >> 11;
  int k = ks * 16 + ((l >> 5) << 3) + j;
  int o = nt * 32 + (l & 31);
  bp[i] = (bf16_t)a[o * 384 + k];
}

__global__ __launch_bounds__(256) void k_edges(const int* __restrict__ edge,
                                               const int* __restrict__ nhop,
                                               int* __restrict__ sidx,
                                               int* __restrict__ didx, int stride) {
  int e = blockIdx.x * 256 + threadIdx.x;
  if (e >= E_TOT) return;
  if (e < E1N) {
    sidx[e] = edge[(size_t)e * stride];
    didx[e] = edge[(size_t)(E1N + e) * stride];
  } else {
    int t = e - E1N;
    sidx[e] = nhop[(size_t)t * stride];
    didx[e] = nhop[(size_t)(E2N + t) * stride];
  }
}

// Edge-MLP GEMM, no LDS: A-fragments straight from global (f32 -> bf16 in reg),
// B pre-packed in fragment order (L2-resident). One wave = 32 edges x 128 out.
// ACCUM=false: edge_e = exp(-lrelu(lrelu(C)@a2)), fused atomic a_rowsum[dst].
// ACCUM=true : w = rel_att*new_rank[src] inline; atomicAdd lrelu(C)*w to hout.
template <bool ACCUM>
__global__ __launch_bounds__(256, 3) void k_gemm(
    const float* __restrict__ input, const float* __restrict__ eemb,
    const float* __restrict__ eembn, const int* __restrict__ sidx,
    const int* __restrict__ didx, const bf16_t* __restrict__ bpack,
    const float* __restrict__ a2, float* __restrict__ edge_e,
    float* __restrict__ a_rowsum, const float* __restrict__ rel_att,
    const float* __restrict__ new_rank, float* __restrict__ hout) {
  const int tid = threadIdx.x;
  const int lane = tid & 63;
  const int wv = tid >> 6;
  const long long e0w = (long long)blockIdx.x * 128 + wv * 32;
  if (e0w >= E_TOT) return;  // waves are all-active or all-empty (E%32==0)
  const int m = lane & 31;
  const int hi2 = lane >> 5;
  const long long e = e0w + m;
  const int s = sidx[e];
  const int d = didx[e];
  // three 128-float segment base pointers for this lane's edge row
  const float* b0 = input + (size_t)s * 128;
  const float* b1 = input + (size_t)d * 128;
  const float* b2 = (e < E1N) ? (eemb + (size_t)e * 128)
                              : (eembn + (size_t)(e - E1N) * 128);
  const int koff = hi2 << 3;

  const bf16x8* __restrict__ bp = (const bf16x8*)bpack;

  f32x16 acc[4];
#pragma unroll
  for (int nt = 0; nt < 4; ++nt)
#pragma unroll
    for (int r = 0; r < 16; ++r) acc[nt][r] = 0.f;

  auto loadA = [&](int ks) -> bf16x8 {
    const float* p = (ks < 8 ? b0 : (ks < 16 ? b1 : b2)) + ((ks & 7) << 4) + koff;
    float4 u0 = *(const float4*)p;
    float4 u1 = *(const float4*)(p + 4);
    bf16x8 r = {(bf16_t)u0.x, (bf16_t)u0.y, (bf16_t)u0.z, (bf16_t)u0.w,
                (bf16_t)u1.x, (bf16_t)u1.y, (bf16_t)u1.z, (bf16_t)u1.w};
    return r;
  };

  bf16x8 a_cur = loadA(0);
  bf16x8 bb[4], bn[4];
#pragma unroll
  for (int nt = 0; nt < 4; ++nt) bb[nt] = bp[nt * 64 + lane];

#pragma unroll
  for (int ks = 0; ks < 24; ++ks) {
    bf16x8 a_nxt;
    if (ks < 23) {
      a_nxt = loadA(ks + 1);
#pragma unroll
      for (int nt = 0; nt < 4; ++nt) bn[nt] = bp[((ks + 1) * 4 + nt) * 64 + lane];
    }
#pragma unroll
    for (int nt = 0; nt < 4; ++nt)
      acc[nt] = __builtin_amdgcn_mfma_f32_32x32x16_bf16(a_cur, bb[nt], acc[nt], 0, 0, 0);
    a_cur = a_nxt;
#pragma unroll
    for (int nt = 0; nt < 4; ++nt) bb[nt] = bn[nt];
  }
  // C layout: col = m (out-feature within nt*32), row = (r&3)+8*(r>>2)+4*hi2 (edge)

  if (!ACCUM) {
    float sacc[16];
#pragma unroll
    for (int r = 0; r < 16; ++r) sacc[r] = 0.f;
#pragma unroll
    for (int nt = 0; nt < 4; ++nt) {
      float a2v = a2[nt * 32 + m];
#pragma unroll
      for (int r = 0; r < 16; ++r) sacc[r] += lrelu(acc[nt][r]) * a2v;
    }
#pragma unroll
    for (int off = 1; off < 32; off <<= 1) {
#pragma unroll
      for (int r = 0; r < 16; ++r) sacc[r] += __shfl_xor(sacc[r], off, 64);
    }
    if (m == 0) {  // lanes 0 and 32 hold the 16 row-sums of their half
#pragma unroll
      for (int r = 0; r < 16; ++r) {
        int row = (r & 3) + ((r >> 2) << 3) + (hi2 << 2);
        long long ee_i = e0w + row;
        float ev = expf(-lrelu(sacc[r]));
        edge_e[ee_i] = ev;
        atomicAdd(&a_rowsum[didx[ee_i]], ev);
      }
    }
  } else {
    float w_m = rel_att[e] * new_rank[s];
    float wr[16];
    int dr[16];
#pragma unroll
    for (int r = 0; r < 16; ++r) {
      int row = (r & 3) + ((r >> 2) << 3) + (hi2 << 2);
      wr[r] = __shfl(w_m, row, 64);
      dr[r] = __shfl(d, row, 64);
    }
#pragma unroll
    for (int nt = 0; nt < 4; ++nt) {
      int o = nt * 32 + m;
#pragma unroll
      for (int r = 0; r < 16; ++r)
        atomicAdd(&hout[(size_t)dr[r] * 128 + o], lrelu(acc[nt][r]) * wr[r]);
    }
  }
}

__global__ __launch_bounds__(256) void k_relatt(const float* __restrict__ edge_e,
                                                const int* __restrict__ didx,
                                                const int* __restrict__ sidx,
                                                const float* __restrict__ a_rowsum,
                                                float* __restrict__ rel_att,
                                                float* __restrict__ e_rowsum) {
  int e = blockIdx.x * 256 + threadIdx.x;
  if (e >= E_TOT) return;
  float rs = a_rowsum[didx[e]];
  rs = (rs == 0.f) ? EPSC : rs;
  float r = edge_e[e] / rs;
  rel_att[e] = r;
  atomicAdd(&e_rowsum[sidx[e]], r);
}

__global__ __launch_bounds__(256) void k_val(const float* __restrict__ rel_att,
                                             const int* __restrict__ sidx,
                                             const int* __restrict__ didx,
                                             const float* __restrict__ rank,
                                             const float* __restrict__ e_rowsum,
                                             float* __restrict__ e_colsum) {
  int e = blockIdx.x * 256 + threadIdx.x;
  if (e >= E_TOT) return;
  int s = sidx[e];
  float er = e_rowsum[s];
  er = (er == 0.f) ? EPSC : er;
  float val = rel_att[e] * rank[s] / er;
  atomicAdd(&e_colsum[didx[e]], val);
}

__global__ __launch_bounds__(256) void k_rank(const float* __restrict__ e_colsum,
                                              float* __restrict__ new_rank,
                                              float* __restrict__ out_tail) {
  int n = blockIdx.x * 256 + threadIdx.x;
  if (n >= N_NODES) return;
  float nr = 1.f - DAMP + DAMP * e_colsum[n];
  new_rank[n] = nr;
  out_tail[n] = nr;
}

__global__ __launch_bounds__(256) void k_elu(float* __restrict__ h) {
  int i = blockIdx.x * 256 + threadIdx.x;
  if (i < N_NODES * 128) {
    float x = h[i];
    h[i] = x > 0.f ? x : expm1f(x);
  }
}

extern "C" void kernel_launch(void* const* d_in, const int* in_sizes, int n_in,
                              void* d_out, int out_size, void* d_ws, size_t ws_size,
                              hipStream_t stream) {
  const float* input = (const float*)d_in[0];
  const int* edge = (const int*)d_in[1];
  const float* eemb = (const float*)d_in[2];
  const int* enh = (const int*)d_in[3];
  const float* eembn = (const float*)d_in[4];
  const float* rank = (const float*)d_in[5];
  const float* a = (const float*)d_in[6];
  const float* a2 = (const float*)d_in[7];
  float* out = (float*)d_out;

  int estride = (in_sizes[1] == 2 * E1N) ? 1 : 2;

  char* ws = (char*)d_ws;
  bf16_t* bpack = (bf16_t*)(ws);              // 98304 B
  int* sidx = (int*)(ws + 98304);             // 2,000,000 B
  int* didx = (int*)(ws + 2098304);           // 2,000,000 B
  float* edge_e = (float*)(ws + 4098304);     // 2,000,000 B
  float* rel_att = (float*)(ws + 6098304);    // 2,000,000 B
  float* a_rowsum = (float*)(ws + 8098304);   // 200,000 B
  float* e_rowsum = (float*)(ws + 8298304);   // 200,000 B
  float* e_colsum = (float*)(ws + 8498304);   // 200,000 B
  float* new_rank = (float*)(ws + 8698304);   // 200,000 B

  hipMemsetAsync(a_rowsum, 0, 3 * 200000, stream);
  hipMemsetAsync(out, 0, (size_t)N_NODES * 128 * 4, stream);

  k_pack<<<192, 256, 0, stream>>>(a, bpack);
  k_edges<<<(E_TOT + 255) / 256, 256, 0, stream>>>(edge, enh, sidx, didx, estride);

  const int NB = (E_TOT + 127) / 128;  // 128 edges per block (4 waves x 32)
  const int EB = (E_TOT + 255) / 256;
  k_gemm<false><<<NB, 256, 0, stream>>>(input, eemb, eembn, sidx, didx, bpack, a2,
                                        edge_e, a_rowsum, nullptr, nullptr, nullptr);
  k_relatt<<<EB, 256, 0, stream>>>(edge_e, didx, sidx, a_rowsum, rel_att, e_rowsum);
  k_val<<<EB, 256, 0, stream>>>(rel_att, sidx, didx, rank, e_rowsum, e_colsum);
  k_rank<<<(N_NODES + 255) / 256, 256, 0, stream>>>(e_colsum, new_rank,
                                                    out + (size_t)N_NODES * 128);
  k_gemm<true><<<NB, 256, 0, stream>>>(input, eemb, eembn, sidx, didx, bpack, a2,
                                       nullptr, nullptr, rel_att, new_rank, out);
  k_elu<<<(N_NODES * 128 + 255) / 256, 256, 0, stream>>>(out);
}

// Round 3
// 789.358 us; speedup vs baseline: 1.4300x; 1.0708x over previous
//
#include <hip/hip_runtime.h>
#include <math.h>

#define N_NODES 50000
#define E1N 400000
#define E2N 100000
#define E_TOT 500000
#define ALPHAC 0.2f
#define DAMP 0.85f
#define EPSC 1e-12f

typedef __bf16 bf16_t;
typedef __bf16 bf16x4 __attribute__((ext_vector_type(4)));
typedef __bf16 bf16x8 __attribute__((ext_vector_type(8)));
typedef float f32x16 __attribute__((ext_vector_type(16)));

__device__ __forceinline__ float lrelu(float x) { return x > 0.f ? x : ALPHAC * x; }

// Pack [a1|a2] (K=128, N=256) into 32x32x16 B-fragment order for k_uv.
// c = nt*32+(l&31): c<128 -> U col (a[c][k]), c>=128 -> V col (a[c-128][128+k])
__global__ __launch_bounds__(256) void k_pack12(const float* __restrict__ a,
                                                bf16_t* __restrict__ bp) {
  int i = blockIdx.x * 256 + threadIdx.x;  // 8*8*64*8 = 32768
  if (i >= 32768) return;
  int j = i & 7;
  int l = (i >> 3) & 63;
  int nt = (i >> 9) & 7;
  int ks = i >> 12;
  int c = nt * 32 + (l & 31);
  int o = (c < 128) ? c : c - 128;
  int koff = (c < 128) ? 0 : 128;
  int k = ks * 16 + ((l >> 5) << 3) + j;
  bp[i] = (bf16_t)a[o * 384 + koff + k];
}

// Pack a3 (K=128, N=128) B-fragments for the emb MFMA in k_pass.
__global__ __launch_bounds__(256) void k_pack3(const float* __restrict__ a,
                                               bf16_t* __restrict__ bp) {
  int i = blockIdx.x * 256 + threadIdx.x;  // 8*4*64*8 = 16384
  if (i >= 16384) return;
  int j = i & 7;
  int l = (i >> 3) & 63;
  int nt = (i >> 9) & 3;
  int ks = i >> 11;
  int o = nt * 32 + (l & 31);
  int k = ks * 16 + ((l >> 5) << 3) + j;
  bp[i] = (bf16_t)a[o * 384 + 256 + k];
}

__global__ __launch_bounds__(256) void k_edges(const int* __restrict__ edge,
                                               const int* __restrict__ nhop,
                                               int* __restrict__ sidx,
                                               int* __restrict__ didx, int stride) {
  int e = blockIdx.x * 256 + threadIdx.x;
  if (e >= E_TOT) return;
  if (e < E1N) {
    sidx[e] = edge[(size_t)e * stride];
    didx[e] = edge[(size_t)(E1N + e) * stride];
  } else {
    int t = e - E1N;
    sidx[e] = nhop[(size_t)t * stride];
    didx[e] = nhop[(size_t)(E2N + t) * stride];
  }
}

// UV = input @ [a1|a2].T  -> bf16 [N_NODES][256]. Streaming rows, tiny kernel.
__global__ __launch_bounds__(256) void k_uv(const float* __restrict__ input,
                                            const bf16_t* __restrict__ bp12,
                                            bf16_t* __restrict__ uv) {
  const int tid = threadIdx.x, lane = tid & 63, wv = tid >> 6;
  const int n0 = blockIdx.x * 128 + wv * 32;
  const int m = lane & 31, hi2 = lane >> 5;
  int n = n0 + m;
  if (n >= N_NODES) n = 0;  // clamped (store is guarded)
  const float* ar = input + (size_t)n * 128 + hi2 * 8;
  const bf16x8* bp = (const bf16x8*)bp12;

  f32x16 acc[8];
#pragma unroll
  for (int nt = 0; nt < 8; ++nt)
#pragma unroll
    for (int r = 0; r < 16; ++r) acc[nt][r] = 0.f;

#pragma unroll
  for (int ks = 0; ks < 8; ++ks) {
    float4 u0 = *(const float4*)(ar + ks * 16);
    float4 u1 = *(const float4*)(ar + ks * 16 + 4);
    bf16x8 af = {(bf16_t)u0.x, (bf16_t)u0.y, (bf16_t)u0.z, (bf16_t)u0.w,
                 (bf16_t)u1.x, (bf16_t)u1.y, (bf16_t)u1.z, (bf16_t)u1.w};
#pragma unroll
    for (int nt = 0; nt < 8; ++nt)
      acc[nt] = __builtin_amdgcn_mfma_f32_32x32x16_bf16(af, bp[(ks * 8 + nt) * 64 + lane],
                                                        acc[nt], 0, 0, 0);
  }
#pragma unroll
  for (int nt = 0; nt < 8; ++nt)
#pragma unroll
    for (int r = 0; r < 16; ++r) {
      int row = (r & 3) + ((r >> 2) << 3) + (hi2 << 2);
      int node = n0 + row;
      if (node < N_NODES) uv[(size_t)node * 256 + nt * 32 + m] = (bf16_t)acc[nt][r];
    }
}

// Per 128-edge block: LDS-stage SUM=U[src]+V[dst] (coalesced row reads), MFMA
// the emb third (contiguous rows, streaming), epilogue as round 2.
template <bool ACCUM>
__global__ __launch_bounds__(256, 3) void k_pass(
    const float* __restrict__ eemb, const float* __restrict__ eembn,
    const bf16_t* __restrict__ uv, const int* __restrict__ sidx,
    const int* __restrict__ didx, const bf16_t* __restrict__ bp3,
    const float* __restrict__ a2, float* __restrict__ edge_e,
    float* __restrict__ a_rowsum, const float* __restrict__ rel_att,
    const float* __restrict__ new_rank, float* __restrict__ hout) {
  __shared__ bf16_t s_sum[128][136];  // pad 8 bf16
  const int tid = threadIdx.x;
  const long long e0 = (long long)blockIdx.x * 128;

  {  // stage: group g (32 lanes) covers one edge row per iter, 8 B/lane
    const int g = tid >> 5;
    const int cl = (tid & 31) * 4;
#pragma unroll
    for (int i = 0; i < 16; ++i) {
      int el = i * 8 + g;
      long long e = e0 + el;
      float sx = 0.f, sy = 0.f, sz = 0.f, sw = 0.f;
      if (e < E_TOT) {
        int s = sidx[e], d = didx[e];
        bf16x4 u = *(const bf16x4*)(uv + (size_t)s * 256 + cl);
        bf16x4 v = *(const bf16x4*)(uv + (size_t)d * 256 + 128 + cl);
        sx = (float)u[0] + (float)v[0];
        sy = (float)u[1] + (float)v[1];
        sz = (float)u[2] + (float)v[2];
        sw = (float)u[3] + (float)v[3];
      }
      bf16x4 o = {(bf16_t)sx, (bf16_t)sy, (bf16_t)sz, (bf16_t)sw};
      *(bf16x4*)&s_sum[el][cl] = o;
    }
  }
  __syncthreads();

  const int lane = tid & 63;
  const int wv = tid >> 6;
  const long long e0w = e0 + wv * 32;
  if (e0w >= E_TOT) return;  // E%32==0: active waves fully valid
  const int m = lane & 31, hi2 = lane >> 5;
  const long long e = e0w + m;
  const float* b2 = (e < E1N) ? (eemb + (size_t)e * 128)
                              : (eembn + (size_t)(e - E1N) * 128);
  const float* ar = b2 + hi2 * 8;

  const bf16x8* bp = (const bf16x8*)bp3;
  f32x16 acc[4];
#pragma unroll
  for (int nt = 0; nt < 4; ++nt)
#pragma unroll
    for (int r = 0; r < 16; ++r) acc[nt][r] = 0.f;

  auto loadA = [&](int ks) -> bf16x8 {
    float4 u0 = *(const float4*)(ar + ks * 16);
    float4 u1 = *(const float4*)(ar + ks * 16 + 4);
    bf16x8 rr = {(bf16_t)u0.x, (bf16_t)u0.y, (bf16_t)u0.z, (bf16_t)u0.w,
                 (bf16_t)u1.x, (bf16_t)u1.y, (bf16_t)u1.z, (bf16_t)u1.w};
    return rr;
  };

  bf16x8 a_cur = loadA(0);
  bf16x8 bb[4], bn[4];
#pragma unroll
  for (int nt = 0; nt < 4; ++nt) bb[nt] = bp[nt * 64 + lane];

#pragma unroll
  for (int ks = 0; ks < 8; ++ks) {
    bf16x8 a_nxt;
    if (ks < 7) {
      a_nxt = loadA(ks + 1);
#pragma unroll
      for (int nt = 0; nt < 4; ++nt) bn[nt] = bp[((ks + 1) * 4 + nt) * 64 + lane];
    }
#pragma unroll
    for (int nt = 0; nt < 4; ++nt)
      acc[nt] = __builtin_amdgcn_mfma_f32_32x32x16_bf16(a_cur, bb[nt], acc[nt], 0, 0, 0);
    a_cur = a_nxt;
#pragma unroll
    for (int nt = 0; nt < 4; ++nt) bb[nt] = bn[nt];
  }
  // C layout: col = nt*32+m, row = (r&3)+8*(r>>2)+4*hi2

  if (!ACCUM) {
    float sac[16];
#pragma unroll
    for (int r = 0; r < 16; ++r) sac[r] = 0.f;
#pragma unroll
    for (int nt = 0; nt < 4; ++nt) {
      float a2v = a2[nt * 32 + m];
      int o = nt * 32 + m;
#pragma unroll
      for (int r = 0; r < 16; ++r) {
        int row = (r & 3) + ((r >> 2) << 3) + (hi2 << 2);
        float c = acc[nt][r] + (float)s_sum[wv * 32 + row][o];
        sac[r] += lrelu(c) * a2v;
      }
    }
#pragma unroll
    for (int off = 1; off < 32; off <<= 1) {
#pragma unroll
      for (int r = 0; r < 16; ++r) sac[r] += __shfl_xor(sac[r], off, 64);
    }
    if (m == 0) {
#pragma unroll
      for (int r = 0; r < 16; ++r) {
        int row = (r & 3) + ((r >> 2) << 3) + (hi2 << 2);
        long long ee_i = e0w + row;
        float ev = expf(-lrelu(sac[r]));
        edge_e[ee_i] = ev;
        atomicAdd(&a_rowsum[didx[ee_i]], ev);
      }
    }
  } else {
    float w_m = rel_att[e] * new_rank[sidx[e]];
    int d = didx[e];
    float wr[16];
    int dr[16];
#pragma unroll
    for (int r = 0; r < 16; ++r) {
      int row = (r & 3) + ((r >> 2) << 3) + (hi2 << 2);
      wr[r] = __shfl(w_m, row, 64);
      dr[r] = __shfl(d, row, 64);
    }
#pragma unroll
    for (int nt = 0; nt < 4; ++nt) {
      int o = nt * 32 + m;
#pragma unroll
      for (int r = 0; r < 16; ++r) {
        int row = (r & 3) + ((r >> 2) << 3) + (hi2 << 2);
        float c = acc[nt][r] + (float)s_sum[wv * 32 + row][o];
        atomicAdd(&hout[(size_t)dr[r] * 128 + o], lrelu(c) * wr[r]);
      }
    }
  }
}

__global__ __launch_bounds__(256) void k_relatt(const float* __restrict__ edge_e,
                                                const int* __restrict__ didx,
                                                const int* __restrict__ sidx,
                                                const float* __restrict__ a_rowsum,
                                                float* __restrict__ rel_att,
                                                float* __restrict__ e_rowsum) {
  int e = blockIdx.x * 256 + threadIdx.x;
  if (e >= E_TOT) return;
  float rs = a_rowsum[didx[e]];
  rs = (rs == 0.f) ? EPSC : rs;
  float r = edge_e[e] / rs;
  rel_att[e] = r;
  atomicAdd(&e_rowsum[sidx[e]], r);
}

__global__ __launch_bounds__(256) void k_val(const float* __restrict__ rel_att,
                                             const int* __restrict__ sidx,
                                             const int* __restrict__ didx,
                                             const float* __restrict__ rank,
                                             const float* __restrict__ e_rowsum,
                                             float* __restrict__ e_colsum) {
  int e = blockIdx.x * 256 + threadIdx.x;
  if (e >= E_TOT) return;
  int s = sidx[e];
  float er = e_rowsum[s];
  er = (er == 0.f) ? EPSC : er;
  float val = rel_att[e] * rank[s] / er;
  atomicAdd(&e_colsum[didx[e]], val);
}

__global__ __launch_bounds__(256) void k_rank(const float* __restrict__ e_colsum,
                                              float* __restrict__ new_rank,
                                              float* __restrict__ out_tail) {
  int n = blockIdx.x * 256 + threadIdx.x;
  if (n >= N_NODES) return;
  float nr = 1.f - DAMP + DAMP * e_colsum[n];
  new_rank[n] = nr;
  out_tail[n] = nr;
}

__global__ __launch_bounds__(256) void k_elu(float* __restrict__ h) {
  int i = blockIdx.x * 256 + threadIdx.x;
  if (i < N_NODES * 128) {
    float x = h[i];
    h[i] = x > 0.f ? x : expm1f(x);
  }
}

extern "C" void kernel_launch(void* const* d_in, const int* in_sizes, int n_in,
                              void* d_out, int out_size, void* d_ws, size_t ws_size,
                              hipStream_t stream) {
  const float* input = (const float*)d_in[0];
  const int* edge = (const int*)d_in[1];
  const float* eemb = (const float*)d_in[2];
  const int* enh = (const int*)d_in[3];
  const float* eembn = (const float*)d_in[4];
  const float* rank = (const float*)d_in[5];
  const float* a = (const float*)d_in[6];
  const float* a2 = (const float*)d_in[7];
  float* out = (float*)d_out;

  int estride = (in_sizes[1] == 2 * E1N) ? 1 : 2;

  char* ws = (char*)d_ws;
  bf16_t* bp12 = (bf16_t*)(ws);                  //    65,536 B
  bf16_t* bp3 = (bf16_t*)(ws + 65536);           //    32,768 B
  bf16_t* uv = (bf16_t*)(ws + 98304);            // 25,600,000 B
  int* sidx = (int*)(ws + 25698304);             //  2,000,000 B
  int* didx = (int*)(ws + 27698304);             //  2,000,000 B
  float* edge_e = (float*)(ws + 29698304);       //  2,000,000 B
  float* rel_att = (float*)(ws + 31698304);      //  2,000,000 B
  float* a_rowsum = (float*)(ws + 33698304);     //    200,000 B
  float* e_rowsum = (float*)(ws + 33898304);     //    200,000 B
  float* e_colsum = (float*)(ws + 34098304);     //    200,000 B
  float* new_rank = (float*)(ws + 34298304);     //    200,000 B

  hipMemsetAsync(a_rowsum, 0, 3 * 200000, stream);
  hipMemsetAsync(out, 0, (size_t)N_NODES * 128 * 4, stream);

  k_pack12<<<128, 256, 0, stream>>>(a, bp12);
  k_pack3<<<64, 256, 0, stream>>>(a, bp3);
  k_edges<<<(E_TOT + 255) / 256, 256, 0, stream>>>(edge, enh, sidx, didx, estride);
  k_uv<<<(N_NODES + 127) / 128, 256, 0, stream>>>(input, bp12, uv);

  const int NB = (E_TOT + 127) / 128;
  const int EB = (E_TOT + 255) / 256;
  k_pass<false><<<NB, 256, 0, stream>>>(eemb, eembn, uv, sidx, didx, bp3, a2,
                                        edge_e, a_rowsum, nullptr, nullptr, nullptr);
  k_relatt<<<EB, 256, 0, stream>>>(edge_e, didx, sidx, a_rowsum, rel_att, e_rowsum);
  k_val<<<EB, 256, 0, stream>>>(rel_att, sidx, didx, rank, e_rowsum, e_colsum);
  k_rank<<<(N_NODES + 255) / 256, 256, 0, stream>>>(e_colsum, new_rank,
                                                    out + (size_t)N_NODES * 128);
  k_pass<true><<<NB, 256, 0, stream>>>(eemb, eembn, uv, sidx, didx, bp3, a2,
                                       nullptr, nullptr, rel_att, new_rank, out);
  k_elu<<<(N_NODES * 128 + 255) / 256, 256, 0, stream>>>(out);
}

// Round 4
// 743.531 us; speedup vs baseline: 1.5182x; 1.0616x over previous
//
#include <hip/hip_runtime.h>
#include <math.h>

#define N_NODES 50000
#define E1N 400000
#define E2N 100000
#define E_TOT 500000
#define ALPHAC 0.2f
#define DAMP 0.85f
#define EPSC 1e-12f

typedef __bf16 bf16_t;
typedef __bf16 bf16x4 __attribute__((ext_vector_type(4)));
typedef __bf16 bf16x8 __attribute__((ext_vector_type(8)));
typedef float f32x16 __attribute__((ext_vector_type(16)));

__device__ __forceinline__ float lrelu(float x) { return x > 0.f ? x : ALPHAC * x; }

// Pack [a1|a2] (K=128, N=256) into 32x32x16 B-fragment order for k_uv.
__global__ __launch_bounds__(256) void k_pack12(const float* __restrict__ a,
                                                bf16_t* __restrict__ bp) {
  int i = blockIdx.x * 256 + threadIdx.x;  // 32768
  if (i >= 32768) return;
  int j = i & 7;
  int l = (i >> 3) & 63;
  int nt = (i >> 9) & 7;
  int ks = i >> 12;
  int c = nt * 32 + (l & 31);
  int o = (c < 128) ? c : c - 128;
  int koff = (c < 128) ? 0 : 128;
  int k = ks * 16 + ((l >> 5) << 3) + j;
  bp[i] = (bf16_t)a[o * 384 + koff + k];
}

// Pack a3 (K=128, N=128) B-fragments for the emb MFMA.
__global__ __launch_bounds__(256) void k_pack3(const float* __restrict__ a,
                                               bf16_t* __restrict__ bp) {
  int i = blockIdx.x * 256 + threadIdx.x;  // 16384
  if (i >= 16384) return;
  int j = i & 7;
  int l = (i >> 3) & 63;
  int nt = (i >> 9) & 3;
  int ks = i >> 11;
  int o = nt * 32 + (l & 31);
  int k = ks * 16 + ((l >> 5) << 3) + j;
  bp[i] = (bf16_t)a[o * 384 + 256 + k];
}

// Edge index split + fused dst-degree count (cnt pre-zeroed).
__global__ __launch_bounds__(256) void k_edges(const int* __restrict__ edge,
                                               const int* __restrict__ nhop,
                                               int* __restrict__ sidx,
                                               int* __restrict__ didx, int stride,
                                               int* __restrict__ cnt) {
  int e = blockIdx.x * 256 + threadIdx.x;
  if (e >= E_TOT) return;
  int s, d;
  if (e < E1N) {
    s = edge[(size_t)e * stride];
    d = edge[(size_t)(E1N + e) * stride];
  } else {
    int t = e - E1N;
    s = nhop[(size_t)t * stride];
    d = nhop[(size_t)(E2N + t) * stride];
  }
  sidx[e] = s;
  didx[e] = d;
  if (cnt) atomicAdd(&cnt[d], 1);
}

// Single-block exclusive scan of cnt[50000] -> csr_start, cursor.
__global__ __launch_bounds__(256) void k_scan(const int* __restrict__ cnt,
                                              int* __restrict__ csr_start,
                                              int* __restrict__ cursor) {
  __shared__ int ls[256];
  __shared__ int lofs[256];
  int t = threadIdx.x;
  int lo = t * 196, hi = lo + 196;
  if (hi > N_NODES) hi = N_NODES;
  int s = 0;
  for (int i = lo; i < hi; ++i) s += cnt[i];
  ls[t] = s;
  __syncthreads();
  if (t == 0) {
    int run = 0;
    for (int i = 0; i < 256; ++i) { lofs[i] = run; run += ls[i]; }
  }
  __syncthreads();
  int run = lofs[t];
  for (int i = lo; i < hi; ++i) {
    csr_start[i] = run;
    cursor[i] = run;
    run += cnt[i];
  }
}

// Scatter edge ids into dst-sorted order (order within segment irrelevant).
__global__ __launch_bounds__(256) void k_pos(const int* __restrict__ didx,
                                             int* __restrict__ cursor,
                                             int* __restrict__ eid) {
  int e = blockIdx.x * 256 + threadIdx.x;
  if (e >= E_TOT) return;
  int pos = atomicAdd(&cursor[didx[e]], 1);
  eid[pos] = e;
}

// UV = input @ [a1|a2].T -> bf16 [N_NODES][256].
__global__ __launch_bounds__(256) void k_uv(const float* __restrict__ input,
                                            const bf16_t* __restrict__ bp12,
                                            bf16_t* __restrict__ uv) {
  const int tid = threadIdx.x, lane = tid & 63, wv = tid >> 6;
  const int n0 = blockIdx.x * 128 + wv * 32;
  const int m = lane & 31, hi2 = lane >> 5;
  int n = n0 + m;
  if (n >= N_NODES) n = 0;
  const float* ar = input + (size_t)n * 128 + hi2 * 8;
  const bf16x8* bp = (const bf16x8*)bp12;

  f32x16 acc[8];
#pragma unroll
  for (int nt = 0; nt < 8; ++nt)
#pragma unroll
    for (int r = 0; r < 16; ++r) acc[nt][r] = 0.f;

#pragma unroll
  for (int ks = 0; ks < 8; ++ks) {
    float4 u0 = *(const float4*)(ar + ks * 16);
    float4 u1 = *(const float4*)(ar + ks * 16 + 4);
    bf16x8 af = {(bf16_t)u0.x, (bf16_t)u0.y, (bf16_t)u0.z, (bf16_t)u0.w,
                 (bf16_t)u1.x, (bf16_t)u1.y, (bf16_t)u1.z, (bf16_t)u1.w};
#pragma unroll
    for (int nt = 0; nt < 8; ++nt)
      acc[nt] = __builtin_amdgcn_mfma_f32_32x32x16_bf16(af, bp[(ks * 8 + nt) * 64 + lane],
                                                        acc[nt], 0, 0, 0);
  }
#pragma unroll
  for (int nt = 0; nt < 8; ++nt)
#pragma unroll
    for (int r = 0; r < 16; ++r) {
      int row = (r & 3) + ((r >> 2) << 3) + (hi2 << 2);
      int node = n0 + row;
      if (node < N_NODES) uv[(size_t)node * 256 + nt * 32 + m] = (bf16_t)acc[nt][r];
    }
}

// Pass 1: C = U[src]+V[dst] (LDS) + emb@a3 (MFMA). Stores P=lrelu(C) bf16 in
// C-fragment tile layout: P[tile*4096 + (nt*16+r)*64 + lane], 128B-coalesced.
// Also edge_e = exp(-lrelu(P . a2)) + atomic a_rowsum[dst].
__global__ __launch_bounds__(256, 3) void k_passA(
    const float* __restrict__ eemb, const float* __restrict__ eembn,
    const bf16_t* __restrict__ uv, const int* __restrict__ sidx,
    const int* __restrict__ didx, const bf16_t* __restrict__ bp3,
    const float* __restrict__ a2, float* __restrict__ edge_e,
    float* __restrict__ a_rowsum, bf16_t* __restrict__ P) {
  __shared__ bf16_t s_sum[128][136];
  const int tid = threadIdx.x;
  const long long e0 = (long long)blockIdx.x * 128;

  {
    const int g = tid >> 5;
    const int cl = (tid & 31) * 4;
#pragma unroll
    for (int i = 0; i < 16; ++i) {
      int el = i * 8 + g;
      long long e = e0 + el;
      float sx = 0.f, sy = 0.f, sz = 0.f, sw = 0.f;
      if (e < E_TOT) {
        int s = sidx[e], d = didx[e];
        bf16x4 u = *(const bf16x4*)(uv + (size_t)s * 256 + cl);
        bf16x4 v = *(const bf16x4*)(uv + (size_t)d * 256 + 128 + cl);
        sx = (float)u[0] + (float)v[0];
        sy = (float)u[1] + (float)v[1];
        sz = (float)u[2] + (float)v[2];
        sw = (float)u[3] + (float)v[3];
      }
      bf16x4 o = {(bf16_t)sx, (bf16_t)sy, (bf16_t)sz, (bf16_t)sw};
      *(bf16x4*)&s_sum[el][cl] = o;
    }
  }
  __syncthreads();

  const int lane = tid & 63;
  const int wv = tid >> 6;
  const long long e0w = e0 + wv * 32;
  if (e0w >= E_TOT) return;
  const int m = lane & 31, hi2 = lane >> 5;
  const long long e = e0w + m;
  const float* b2 = (e < E1N) ? (eemb + (size_t)e * 128)
                              : (eembn + (size_t)(e - E1N) * 128);
  const float* ar = b2 + hi2 * 8;

  const bf16x8* bp = (const bf16x8*)bp3;
  f32x16 acc[4];
#pragma unroll
  for (int nt = 0; nt < 4; ++nt)
#pragma unroll
    for (int r = 0; r < 16; ++r) acc[nt][r] = 0.f;

  auto loadA = [&](int ks) -> bf16x8 {
    float4 u0 = *(const float4*)(ar + ks * 16);
    float4 u1 = *(const float4*)(ar + ks * 16 + 4);
    bf16x8 rr = {(bf16_t)u0.x, (bf16_t)u0.y, (bf16_t)u0.z, (bf16_t)u0.w,
                 (bf16_t)u1.x, (bf16_t)u1.y, (bf16_t)u1.z, (bf16_t)u1.w};
    return rr;
  };

  bf16x8 a_cur = loadA(0);
  bf16x8 bb[4], bn[4];
#pragma unroll
  for (int nt = 0; nt < 4; ++nt) bb[nt] = bp[nt * 64 + lane];

#pragma unroll
  for (int ks = 0; ks < 8; ++ks) {
    bf16x8 a_nxt;
    if (ks < 7) {
      a_nxt = loadA(ks + 1);
#pragma unroll
      for (int nt = 0; nt < 4; ++nt) bn[nt] = bp[((ks + 1) * 4 + nt) * 64 + lane];
    }
#pragma unroll
    for (int nt = 0; nt < 4; ++nt)
      acc[nt] = __builtin_amdgcn_mfma_f32_32x32x16_bf16(a_cur, bb[nt], acc[nt], 0, 0, 0);
    a_cur = a_nxt;
#pragma unroll
    for (int nt = 0; nt < 4; ++nt) bb[nt] = bn[nt];
  }

  bf16_t* Pt = P + ((long long)blockIdx.x * 4 + wv) * 4096;
  float sac[16];
#pragma unroll
  for (int r = 0; r < 16; ++r) sac[r] = 0.f;
#pragma unroll
  for (int nt = 0; nt < 4; ++nt) {
    int o = nt * 32 + m;
    float a2v = a2[o];
#pragma unroll
    for (int r = 0; r < 16; ++r) {
      int row = (r & 3) + ((r >> 2) << 3) + (hi2 << 2);
      float c = acc[nt][r] + (float)s_sum[wv * 32 + row][o];
      float p = lrelu(c);
      Pt[(nt * 16 + r) * 64 + lane] = (bf16_t)p;
      sac[r] += p * a2v;
    }
  }
#pragma unroll
  for (int off = 1; off < 32; off <<= 1) {
#pragma unroll
    for (int r = 0; r < 16; ++r) sac[r] += __shfl_xor(sac[r], off, 64);
  }
  if (m == 0) {
#pragma unroll
    for (int r = 0; r < 16; ++r) {
      int row = (r & 3) + ((r >> 2) << 3) + (hi2 << 2);
      long long ee_i = e0w + row;
      float ev = expf(-lrelu(sac[r]));
      edge_e[ee_i] = ev;
      atomicAdd(&a_rowsum[didx[ee_i]], ev);
    }
  }
}

// h_prime: one 32-lane group per dst node; gather its P rows + w, reduce,
// write each output row once, elu fused.
__global__ __launch_bounds__(256) void k_hprime(const bf16_t* __restrict__ P,
                                                const int* __restrict__ eid,
                                                const int* __restrict__ csr_start,
                                                const int* __restrict__ cnt,
                                                const float* __restrict__ w,
                                                float* __restrict__ out) {
  int g = (blockIdx.x << 3) | (threadIdx.x >> 5);
  if (g >= N_NODES) return;
  int m = threadIdx.x & 31;
  int start = csr_start[g], deg = cnt[g];
  float a0 = 0.f, a1 = 0.f, a2v = 0.f, a3v = 0.f;
  for (int i = 0; i < deg; ++i) {
    int e = eid[start + i];
    float we = w[e];
    int row = e & 31;
    int r = (row & 3) | ((row >> 3) << 2);
    int hi2 = (row >> 2) & 1;
    const bf16_t* p = P + (long long)(e >> 5) * 4096 + r * 64 + hi2 * 32 + m;
    a0 += we * (float)p[0];
    a1 += we * (float)p[16 * 64];
    a2v += we * (float)p[32 * 64];
    a3v += we * (float)p[48 * 64];
  }
  float* o = out + (size_t)g * 128 + m;
  o[0] = a0 > 0.f ? a0 : expm1f(a0);
  o[32] = a1 > 0.f ? a1 : expm1f(a1);
  o[64] = a2v > 0.f ? a2v : expm1f(a2v);
  o[96] = a3v > 0.f ? a3v : expm1f(a3v);
}

// ---------- fallback (round-3) recompute-ACCUM pass ----------
template <bool ACCUM>
__global__ __launch_bounds__(256, 3) void k_pass(
    const float* __restrict__ eemb, const float* __restrict__ eembn,
    const bf16_t* __restrict__ uv, const int* __restrict__ sidx,
    const int* __restrict__ didx, const bf16_t* __restrict__ bp3,
    const float* __restrict__ a2, float* __restrict__ edge_e,
    float* __restrict__ a_rowsum, const float* __restrict__ rel_att,
    const float* __restrict__ new_rank, float* __restrict__ hout) {
  __shared__ bf16_t s_sum[128][136];
  const int tid = threadIdx.x;
  const long long e0 = (long long)blockIdx.x * 128;
  {
    const int g = tid >> 5;
    const int cl = (tid & 31) * 4;
#pragma unroll
    for (int i = 0; i < 16; ++i) {
      int el = i * 8 + g;
      long long e = e0 + el;
      float sx = 0.f, sy = 0.f, sz = 0.f, sw = 0.f;
      if (e < E_TOT) {
        int s = sidx[e], d = didx[e];
        bf16x4 u = *(const bf16x4*)(uv + (size_t)s * 256 + cl);
        bf16x4 v = *(const bf16x4*)(uv + (size_t)d * 256 + 128 + cl);
        sx = (float)u[0] + (float)v[0];
        sy = (float)u[1] + (float)v[1];
        sz = (float)u[2] + (float)v[2];
        sw = (float)u[3] + (float)v[3];
      }
      bf16x4 o = {(bf16_t)sx, (bf16_t)sy, (bf16_t)sz, (bf16_t)sw};
      *(bf16x4*)&s_sum[el][cl] = o;
    }
  }
  __syncthreads();

  const int lane = tid & 63;
  const int wv = tid >> 6;
  const long long e0w = e0 + wv * 32;
  if (e0w >= E_TOT) return;
  const int m = lane & 31, hi2 = lane >> 5;
  const long long e = e0w + m;
  const float* b2 = (e < E1N) ? (eemb + (size_t)e * 128)
                              : (eembn + (size_t)(e - E1N) * 128);
  const float* ar = b2 + hi2 * 8;

  const bf16x8* bp = (const bf16x8*)bp3;
  f32x16 acc[4];
#pragma unroll
  for (int nt = 0; nt < 4; ++nt)
#pragma unroll
    for (int r = 0; r < 16; ++r) acc[nt][r] = 0.f;

  auto loadA = [&](int ks) -> bf16x8 {
    float4 u0 = *(const float4*)(ar + ks * 16);
    float4 u1 = *(const float4*)(ar + ks * 16 + 4);
    bf16x8 rr = {(bf16_t)u0.x, (bf16_t)u0.y, (bf16_t)u0.z, (bf16_t)u0.w,
                 (bf16_t)u1.x, (bf16_t)u1.y, (bf16_t)u1.z, (bf16_t)u1.w};
    return rr;
  };

  bf16x8 a_cur = loadA(0);
  bf16x8 bb[4], bn[4];
#pragma unroll
  for (int nt = 0; nt < 4; ++nt) bb[nt] = bp[nt * 64 + lane];

#pragma unroll
  for (int ks = 0; ks < 8; ++ks) {
    bf16x8 a_nxt;
    if (ks < 7) {
      a_nxt = loadA(ks + 1);
#pragma unroll
      for (int nt = 0; nt < 4; ++nt) bn[nt] = bp[((ks + 1) * 4 + nt) * 64 + lane];
    }
#pragma unroll
    for (int nt = 0; nt < 4; ++nt)
      acc[nt] = __builtin_amdgcn_mfma_f32_32x32x16_bf16(a_cur, bb[nt], acc[nt], 0, 0, 0);
    a_cur = a_nxt;
#pragma unroll
    for (int nt = 0; nt < 4; ++nt) bb[nt] = bn[nt];
  }

  if (!ACCUM) {
    float sac[16];
#pragma unroll
    for (int r = 0; r < 16; ++r) sac[r] = 0.f;
#pragma unroll
    for (int nt = 0; nt < 4; ++nt) {
      float a2v = a2[nt * 32 + m];
      int o = nt * 32 + m;
#pragma unroll
      for (int r = 0; r < 16; ++r) {
        int row = (r & 3) + ((r >> 2) << 3) + (hi2 << 2);
        float c = acc[nt][r] + (float)s_sum[wv * 32 + row][o];
        sac[r] += lrelu(c) * a2v;
      }
    }
#pragma unroll
    for (int off = 1; off < 32; off <<= 1) {
#pragma unroll
      for (int r = 0; r < 16; ++r) sac[r] += __shfl_xor(sac[r], off, 64);
    }
    if (m == 0) {
#pragma unroll
      for (int r = 0; r < 16; ++r) {
        int row = (r & 3) + ((r >> 2) << 3) + (hi2 << 2);
        long long ee_i = e0w + row;
        float ev = expf(-lrelu(sac[r]));
        edge_e[ee_i] = ev;
        atomicAdd(&a_rowsum[didx[ee_i]], ev);
      }
    }
  } else {
    float w_m = rel_att[e] * new_rank[sidx[e]];
    int d = didx[e];
    float wr[16];
    int dr[16];
#pragma unroll
    for (int r = 0; r < 16; ++r) {
      int row = (r & 3) + ((r >> 2) << 3) + (hi2 << 2);
      wr[r] = __shfl(w_m, row, 64);
      dr[r] = __shfl(d, row, 64);
    }
#pragma unroll
    for (int nt = 0; nt < 4; ++nt) {
      int o = nt * 32 + m;
#pragma unroll
      for (int r = 0; r < 16; ++r) {
        int row = (r & 3) + ((r >> 2) << 3) + (hi2 << 2);
        float c = acc[nt][r] + (float)s_sum[wv * 32 + row][o];
        atomicAdd(&hout[(size_t)dr[r] * 128 + o], lrelu(c) * wr[r]);
      }
    }
  }
}

__global__ __launch_bounds__(256) void k_relatt(const float* __restrict__ edge_e,
                                                const int* __restrict__ didx,
                                                const int* __restrict__ sidx,
                                                const float* __restrict__ a_rowsum,
                                                float* __restrict__ rel_att,
                                                float* __restrict__ e_rowsum) {
  int e = blockIdx.x * 256 + threadIdx.x;
  if (e >= E_TOT) return;
  float rs = a_rowsum[didx[e]];
  rs = (rs == 0.f) ? EPSC : rs;
  float r = edge_e[e] / rs;
  rel_att[e] = r;
  atomicAdd(&e_rowsum[sidx[e]], r);
}

__global__ __launch_bounds__(256) void k_val(const float* __restrict__ rel_att,
                                             const int* __restrict__ sidx,
                                             const int* __restrict__ didx,
                                             const float* __restrict__ rank,
                                             const float* __restrict__ e_rowsum,
                                             float* __restrict__ e_colsum) {
  int e = blockIdx.x * 256 + threadIdx.x;
  if (e >= E_TOT) return;
  int s = sidx[e];
  float er = e_rowsum[s];
  er = (er == 0.f) ? EPSC : er;
  float val = rel_att[e] * rank[s] / er;
  atomicAdd(&e_colsum[didx[e]], val);
}

__global__ __launch_bounds__(256) void k_rank(const float* __restrict__ e_colsum,
                                              float* __restrict__ new_rank,
                                              float* __restrict__ out_tail) {
  int n = blockIdx.x * 256 + threadIdx.x;
  if (n >= N_NODES) return;
  float nr = 1.f - DAMP + DAMP * e_colsum[n];
  new_rank[n] = nr;
  out_tail[n] = nr;
}

__global__ __launch_bounds__(256) void k_w(const float* __restrict__ rel_att,
                                           const int* __restrict__ sidx,
                                           const float* __restrict__ new_rank,
                                           float* __restrict__ w) {
  int e = blockIdx.x * 256 + threadIdx.x;
  if (e < E_TOT) w[e] = rel_att[e] * new_rank[sidx[e]];
}

__global__ __launch_bounds__(256) void k_elu(float* __restrict__ h) {
  int i = blockIdx.x * 256 + threadIdx.x;
  if (i < N_NODES * 128) {
    float x = h[i];
    h[i] = x > 0.f ? x : expm1f(x);
  }
}

extern "C" void kernel_launch(void* const* d_in, const int* in_sizes, int n_in,
                              void* d_out, int out_size, void* d_ws, size_t ws_size,
                              hipStream_t stream) {
  const float* input = (const float*)d_in[0];
  const int* edge = (const int*)d_in[1];
  const float* eemb = (const float*)d_in[2];
  const int* enh = (const int*)d_in[3];
  const float* eembn = (const float*)d_in[4];
  const float* rank = (const float*)d_in[5];
  const float* a = (const float*)d_in[6];
  const float* a2 = (const float*)d_in[7];
  float* out = (float*)d_out;

  int estride = (in_sizes[1] == 2 * E1N) ? 1 : 2;

  char* ws = (char*)d_ws;
  bf16_t* bp12 = (bf16_t*)(ws);                 //     65,536
  bf16_t* bp3 = (bf16_t*)(ws + 65536);          //     32,768
  bf16_t* uv = (bf16_t*)(ws + 98304);           // 25,600,000
  int* sidx = (int*)(ws + 25698304);            //  2,000,000
  int* didx = (int*)(ws + 27698304);            //  2,000,000
  float* edge_e = (float*)(ws + 29698304);      //  2,000,000
  float* rel_att = (float*)(ws + 31698304);     //  2,000,000
  float* warr = (float*)(ws + 33698304);        //  2,000,000
  int* eid = (int*)(ws + 35698304);             //  2,000,000
  int* csr_start = (int*)(ws + 37698304);       //    200,000
  int* cursor = (int*)(ws + 37898304);          //    200,000
  int* cnt = (int*)(ws + 38098304);             //    200,000
  float* a_rowsum = (float*)(ws + 38298304);    //    200,000
  float* e_rowsum = (float*)(ws + 38498304);    //    200,000
  float* e_colsum = (float*)(ws + 38698304);    //    200,000
  float* new_rank = (float*)(ws + 38898304);    //    200,000
  bf16_t* P = (bf16_t*)(ws + 39098304);         // 128,000,000 -> 167,098,304

  const bool big = ws_size >= 167098304ULL;

  const int NB = (E_TOT + 127) / 128;
  const int EB = (E_TOT + 255) / 256;

  if (big) {
    // zero cnt + a_rowsum + e_rowsum + e_colsum (contiguous)
    hipMemsetAsync(cnt, 0, 4 * 200000, stream);

    k_pack12<<<128, 256, 0, stream>>>(a, bp12);
    k_pack3<<<64, 256, 0, stream>>>(a, bp3);
    k_edges<<<EB, 256, 0, stream>>>(edge, enh, sidx, didx, estride, cnt);
    k_scan<<<1, 256, 0, stream>>>(cnt, csr_start, cursor);
    k_pos<<<EB, 256, 0, stream>>>(didx, cursor, eid);
    k_uv<<<(N_NODES + 127) / 128, 256, 0, stream>>>(input, bp12, uv);

    k_passA<<<NB, 256, 0, stream>>>(eemb, eembn, uv, sidx, didx, bp3, a2,
                                    edge_e, a_rowsum, P);
    k_relatt<<<EB, 256, 0, stream>>>(edge_e, didx, sidx, a_rowsum, rel_att, e_rowsum);
    k_val<<<EB, 256, 0, stream>>>(rel_att, sidx, didx, rank, e_rowsum, e_colsum);
    k_rank<<<(N_NODES + 255) / 256, 256, 0, stream>>>(e_colsum, new_rank,
                                                      out + (size_t)N_NODES * 128);
    k_w<<<EB, 256, 0, stream>>>(rel_att, sidx, new_rank, warr);
    k_hprime<<<(N_NODES + 7) / 8, 256, 0, stream>>>(P, eid, csr_start, cnt, warr, out);
  } else {
    // round-3 fallback: two-pass recompute + atomic hout
    hipMemsetAsync(cnt, 0, 4 * 200000, stream);
    hipMemsetAsync(out, 0, (size_t)N_NODES * 128 * 4, stream);

    k_pack12<<<128, 256, 0, stream>>>(a, bp12);
    k_pack3<<<64, 256, 0, stream>>>(a, bp3);
    k_edges<<<EB, 256, 0, stream>>>(edge, enh, sidx, didx, estride, nullptr);
    k_uv<<<(N_NODES + 127) / 128, 256, 0, stream>>>(input, bp12, uv);

    k_pass<false><<<NB, 256, 0, stream>>>(eemb, eembn, uv, sidx, didx, bp3, a2,
                                          edge_e, a_rowsum, nullptr, nullptr, nullptr);
    k_relatt<<<EB, 256, 0, stream>>>(edge_e, didx, sidx, a_rowsum, rel_att, e_rowsum);
    k_val<<<EB, 256, 0, stream>>>(rel_att, sidx, didx, rank, e_rowsum, e_colsum);
    k_rank<<<(N_NODES + 255) / 256, 256, 0, stream>>>(e_colsum, new_rank,
                                                      out + (size_t)N_NODES * 128);
    k_pass<true><<<NB, 256, 0, stream>>>(eemb, eembn, uv, sidx, didx, bp3, a2,
                                         nullptr, nullptr, rel_att, new_rank, out);
    k_elu<<<(N_NODES * 128 + 255) / 256, 256, 0, stream>>>(out);
  }
}